// Round 15
// baseline (169.353 us; speedup 1.0000x reference)
//
#include <hip/hip_runtime.h>

// ---------------------------------------------------------------------------
// BaseWindowAttention on MI355X (gfx950) — FULLY FUSED single-pass pipeline
// x:[2,256,256,256]f32, w_qkv:[256,768]f32, pos_emb:[15,15]f32,
// w_out:[256,256]f32, b_out:[256]f32, rel_idx:[64,64,2]i32
// out:[2,256,256,256]f32
//
//  prep:  wpk  = w_qkv repacked in MFMA fragment order (coalesced 1KB wave
//                loads), wopk = w_out likewise, biasPC[e][lane] f32.
//  fused: block = 1 window (2048 blocks, 512 thr = 8 waves = 8 heads).
//         R15 = R14 champion + FUSED Q/K ks-loop sharing af reads:
//         phase-2 XA re-reads drop 96 -> 64 b128/wave (LDS was the largest
//         pipe demand, ~36us/CU). Scratch round trips wrQ->rdQ->wrK->rdK
//         through one [64][40] region (per-wave DS in-order; read results
//         consumed after the phase-3 barrier -> no added waits).
//  Occupancy model (m69): VGPR tiers {64,128,256} halve waves/CU. 65-128
//  regs -> 16 waves/CU cap, which 72KB LDS (2 blocks x 8 waves) saturates.
//  launch_bounds(512,4) pins the cap at exactly 128 so the fused loop's
//  64 acc regs can't tip into the 129+ tier (8 waves/CU).
//  Hard lessons: static names for frag arrays (R11/rule #20); coalesced
//  frag loads via pre-packing (R7); never force min-waves beyond natural
//  fit by >~10 regs (R2/R13 spills).
// ---------------------------------------------------------------------------

typedef __bf16 bf16_t;
typedef __bf16 bf16x8 __attribute__((ext_vector_type(8)));
typedef __bf16 bf16x4 __attribute__((ext_vector_type(4)));
typedef float  f32x4  __attribute__((ext_vector_type(4)));

#define MFMA_BF16(a, b, c) __builtin_amdgcn_mfma_f32_16x16x32_bf16((a), (b), (c), 0, 0, 0)
#define SM_SCALE 0.17677669529663687f  // 32^-0.5

// ws layout (bytes)
#define WPK_OFF    0u         // bf16 [8h][3s][2ni][8ks][64 lane][8] = 384KB
#define WOPK_OFF   393216u    // bf16 [8wv][2nj][8ks][64 lane][8]   = 128KB
#define BIASPC_OFF 524288u    // f32  [64 e][64 lane]               = 16KB

// ---------------------------------------------------------------------------
__global__ __launch_bounds__(256) void prep_kernel(
    const float* __restrict__ w_qkv, const float* __restrict__ w_out,
    const float* __restrict__ pos_emb, const int* __restrict__ rel_idx,
    bf16_t* __restrict__ wpk, bf16_t* __restrict__ wopk,
    float* __restrict__ biasPC)
{
    int idx = blockIdx.x * 256 + threadIdx.x;
    if (idx < 196608) {
        // wpk: tile t = ((h*3+s)*2+ni)*8+ks, entry (lane,j)
        // value = w_qkv[k][n], n = s*256+h*32+ni*16+c, k = ks*32+g*8+j
        int j = idx & 7, lane = (idx >> 3) & 63, t = idx >> 9;
        int ks = t & 7, ni = (t >> 3) & 1, hs = t >> 4;
        int s = hs % 3, h = hs / 3;
        int c = lane & 15, g = lane >> 4;
        int n = s * 256 + h * 32 + ni * 16 + c;
        int k = ks * 32 + g * 8 + j;
        wpk[idx] = (bf16_t)w_qkv[k * 768 + n];
    } else if (idx < 262144) {
        // wopk: tile tt = (wv*2+nj)*8+ks, entry (lane,j)
        // value = w_out[k][n], n = 32wv+16nj+c, k = 32ks+8g+j
        int t2 = idx - 196608;
        int j = t2 & 7, lane = (t2 >> 3) & 63, tt = t2 >> 9;
        int ks = tt & 7, nj = (tt >> 3) & 1, wv = tt >> 4;
        int c = lane & 15, g = lane >> 4;
        wopk[t2] = (bf16_t)w_out[(32 * ks + 8 * g + j) * 256 + 32 * wv + 16 * nj + c];
    } else if (idx < 266240) {
        // biasPC[e][lane]: e = (ni,mi,rg) per-lane MFMA layout, transposed
        int t = idx - 262144;
        int e = t >> 6, lane = t & 63;
        int ni = e >> 4, mi = (e >> 2) & 3, rg = e & 3;
        int i = 16 * ni + (lane & 15);          // query index
        int j = 16 * mi + 4 * (lane >> 4) + rg; // key index
        int i0 = rel_idx[(i * 64 + j) * 2 + 0];
        int i1 = rel_idx[(i * 64 + j) * 2 + 1];
        biasPC[t] = pos_emb[i0 * 15 + i1];
    }
}

// ---------------------------------------------------------------------------
// Fully fused window kernel. Grid 2048 (one per window), 512 thr = 8 waves.
__global__ __launch_bounds__(512, 4) void fused_kernel(
    const float* __restrict__ x, const bf16_t* __restrict__ wpk,
    const float* __restrict__ biasPC, const bf16_t* __restrict__ wopk,
    const float* __restrict__ b_out, float* __restrict__ out)
{
    // XA_s: x-tile (phase 1-2), then AO tile (phase 3-4). 32KB.
    __shared__ __align__(16) bf16_t XA_s[64 * 256];
    // per-wave scratch 5KB: Q/K [64][40] | V^T [32][72] | P [2][1024]
    __shared__ __align__(16) bf16_t SB_s[8][2560];

    const int tid = threadIdx.x;
    const int lane = tid & 63, wv = tid >> 6;
    const int g = lane >> 4, c = lane & 15;
    const int b = blockIdx.x;
    const int h = wv;
    const int rbase = (b >> 10) * 65536 + ((b >> 5) & 31) * 2048 + (b & 31) * 8;

    bf16_t* SB = SB_s[wv];
    f32x4 z4 = {0.f, 0.f, 0.f, 0.f};

    // ---- phase 1: x window -> Xs bf16 (2048 x 16B chunks, 4/thread)
#pragma unroll
    for (int jj = 0; jj < 4; ++jj) {
        int q = jj * 512 + tid;          // chunk index 0..2047
        int tok = q >> 5, ci = q & 31;   // 32 chunks per 64-token row
        int r = rbase + (tok >> 3) * 256 + (tok & 7);
        const f32x4* xp = (const f32x4*)(x + (size_t)r * 256 + ci * 8);
        f32x4 a = xp[0], bq = xp[1];
        bf16x8 t;
        t[0] = (bf16_t)a[0];  t[1] = (bf16_t)a[1];
        t[2] = (bf16_t)a[2];  t[3] = (bf16_t)a[3];
        t[4] = (bf16_t)bq[0]; t[5] = (bf16_t)bq[1];
        t[6] = (bf16_t)bq[2]; t[7] = (bf16_t)bq[3];
        *(bf16x8*)(XA_s + tok * 256 + ((ci ^ (tok & 31)) << 3)) = t;
    }
    __syncthreads();

    // ---- phase 2a: FUSED Q+K strips, operand-swapped, shared af reads.
    // acc[ni][mi]: dh = 16ni+4g+rg (rows), tok = 16mi+c (cols)
    bf16x8 qf[4], kf[4], vbA[2][2];
    {
        const bf16_t* wbq = wpk + (size_t)(h * 3 + 0) * 8192;
        const bf16_t* wbk = wpk + (size_t)(h * 3 + 1) * 8192;
        f32x4 accq[2][4], acck[2][4];
#pragma unroll
        for (int i = 0; i < 2; ++i)
#pragma unroll
            for (int j = 0; j < 4; ++j) { accq[i][j] = z4; acck[i][j] = z4; }

#pragma unroll
        for (int ks = 0; ks < 8; ++ks) {
            bf16x8 bq0 = *(const bf16x8*)(wbq + ks * 512 + lane * 8);
            bf16x8 bq1 = *(const bf16x8*)(wbq + (8 + ks) * 512 + lane * 8);
            bf16x8 bk0 = *(const bf16x8*)(wbk + ks * 512 + lane * 8);
            bf16x8 bk1 = *(const bf16x8*)(wbk + (8 + ks) * 512 + lane * 8);
            bf16x8 af[4];
#pragma unroll
            for (int mi = 0; mi < 4; ++mi) {
                int tok = 16 * mi + c;
                af[mi] = *(const bf16x8*)(XA_s + tok * 256 + (((4 * ks + g) ^ (tok & 31)) << 3));
            }
#pragma unroll
            for (int mi = 0; mi < 4; ++mi) {
                accq[0][mi] = MFMA_BF16(bq0, af[mi], accq[0][mi]);
                accq[1][mi] = MFMA_BF16(bq1, af[mi], accq[1][mi]);
                acck[0][mi] = MFMA_BF16(bk0, af[mi], acck[0][mi]);
                acck[1][mi] = MFMA_BF16(bk1, af[mi], acck[1][mi]);
            }
        }
        // scratch round trips through one [64][40] region. Per-wave LDS ops
        // are in-order (rdQ before wrK is safe); results consumed after the
        // phase-3 barrier, so no waits land here. Destinations STATIC.
#pragma unroll
        for (int mi = 0; mi < 4; ++mi)
#pragma unroll
            for (int ni = 0; ni < 2; ++ni) {
                bf16x4 pk;
#pragma unroll
                for (int rg = 0; rg < 4; ++rg) pk[rg] = (bf16_t)accq[ni][mi][rg];
                *(bf16x4*)(SB + (16 * mi + c) * 40 + 16 * ni + 4 * g) = pk;
            }
#pragma unroll
        for (int j = 0; j < 4; ++j)
            qf[j] = *(const bf16x8*)(SB + (16 * j + c) * 40 + 8 * g);
#pragma unroll
        for (int mi = 0; mi < 4; ++mi)
#pragma unroll
            for (int ni = 0; ni < 2; ++ni) {
                bf16x4 pk;
#pragma unroll
                for (int rg = 0; rg < 4; ++rg) pk[rg] = (bf16_t)acck[ni][mi][rg];
                *(bf16x4*)(SB + (16 * mi + c) * 40 + 16 * ni + 4 * g) = pk;
            }
#pragma unroll
        for (int j = 0; j < 4; ++j)
            kf[j] = *(const bf16x8*)(SB + (16 * j + c) * 40 + 8 * g);
    }

    // ---- phase 2b: V strip (standard order), as R14
    {
        const bf16_t* wb = wpk + (size_t)(h * 3 + 2) * 8192;
        bf16x8 bfr[2][8];
#pragma unroll
        for (int ni = 0; ni < 2; ++ni)
#pragma unroll
            for (int ks = 0; ks < 8; ++ks)
                bfr[ni][ks] = *(const bf16x8*)(wb + (ni * 8 + ks) * 512 + lane * 8);

        // acc[mi][ni]: tok = 16mi+4g+rg (rows), dh = 16ni+c (cols)
        f32x4 acc[4][2];
#pragma unroll
        for (int i = 0; i < 4; ++i) { acc[i][0] = z4; acc[i][1] = z4; }
#pragma unroll
        for (int ks = 0; ks < 8; ++ks) {
            bf16x8 af[4];
#pragma unroll
            for (int mi = 0; mi < 4; ++mi) {
                int tok = 16 * mi + c;
                af[mi] = *(const bf16x8*)(XA_s + tok * 256 + (((4 * ks + g) ^ (tok & 31)) << 3));
            }
#pragma unroll
            for (int mi = 0; mi < 4; ++mi) {
                acc[mi][0] = MFMA_BF16(af[mi], bfr[0][ks], acc[mi][0]);
                acc[mi][1] = MFMA_BF16(af[mi], bfr[1][ks], acc[mi][1]);
            }
        }
        // V^T [32][72] scratch: 8 b64 writes, then 4 b128 reads
#pragma unroll
        for (int mi = 0; mi < 4; ++mi)
#pragma unroll
            for (int ni = 0; ni < 2; ++ni) {
                bf16x4 pk;
#pragma unroll
                for (int rg = 0; rg < 4; ++rg) pk[rg] = (bf16_t)acc[mi][ni][rg];
                *(bf16x4*)(SB + (16 * ni + c) * 72 + 16 * mi + 4 * g) = pk;
            }
#pragma unroll
        for (int ks2 = 0; ks2 < 2; ++ks2) {
            vbA[ks2][0] = *(const bf16x8*)(SB + c * 72 + 32 * ks2 + 8 * g);
            vbA[ks2][1] = *(const bf16x8*)(SB + (16 + c) * 72 + 32 * ks2 + 8 * g);
        }
    }
    __syncthreads();   // all waves done with Xs; XA_s becomes AO tile

    // ---- phase 3: attention per head (P dbuf in SB; bias from biasPC)
    bf16_t* Pw = SB;
#pragma unroll
    for (int ni = 0; ni < 4; ++ni) {
        f32x4 s[4];
        __builtin_amdgcn_s_setprio(1);
#pragma unroll
        for (int mi = 0; mi < 4; ++mi)
            s[mi] = MFMA_BF16(kf[mi], qf[ni], z4);
        __builtin_amdgcn_s_setprio(0);

        float mx = -1e30f;
#pragma unroll
        for (int mi = 0; mi < 4; ++mi) {
#pragma unroll
            for (int rg = 0; rg < 4; ++rg) {
                float bb = biasPC[(ni * 16 + mi * 4 + rg) * 64 + lane];
                float t = fmaf(s[mi][rg], SM_SCALE, bb);
                s[mi][rg] = t;
                mx = fmaxf(mx, t);
            }
        }
        mx = fmaxf(mx, __shfl_xor(mx, 16));
        mx = fmaxf(mx, __shfl_xor(mx, 32));
        float sm = 0.f;
#pragma unroll
        for (int mi = 0; mi < 4; ++mi)
#pragma unroll
            for (int rg = 0; rg < 4; ++rg) {
                float p = __expf(s[mi][rg] - mx);
                s[mi][rg] = p;
                sm += p;
            }
        sm += __shfl_xor(sm, 16);
        sm += __shfl_xor(sm, 32);
        float inv = 1.0f / sm;

        bf16_t* Pl = Pw + (ni & 1) * 1024;   // double-buffered 2KB tile
#pragma unroll
        for (int mi = 0; mi < 4; ++mi) {
            bf16x4 pk;
#pragma unroll
            for (int rg = 0; rg < 4; ++rg) pk[rg] = (bf16_t)s[mi][rg];
            *(bf16x4*)(Pl + c * 64 + (((2 * mi + (g >> 1)) ^ (c & 7)) << 3) + 4 * (g & 1)) = pk;
        }

        // O^T = V^T P^T : lane(c,g) -> O^T[dh=16mi+4g+rg][tok=16ni+c]
        f32x4 o0 = z4, o1 = z4;
        __builtin_amdgcn_s_setprio(1);
#pragma unroll
        for (int ks = 0; ks < 2; ++ks) {
            bf16x8 pa = *(const bf16x8*)(Pl + c * 64 + (((4 * ks + g) ^ (c & 7)) << 3));
            o0 = MFMA_BF16(vbA[ks][0], pa, o0);
            o1 = MFMA_BF16(vbA[ks][1], pa, o1);
        }
        __builtin_amdgcn_s_setprio(0);
        // normalize (inv is per q-row, uniform over g) + AO write (b64)
        int tok = 16 * ni + c;
#pragma unroll
        for (int mi = 0; mi < 2; ++mi) {
            f32x4 ov = (mi == 0) ? o0 : o1;
            bf16x4 pk;
#pragma unroll
            for (int rg = 0; rg < 4; ++rg) pk[rg] = (bf16_t)(ov[rg] * inv);
            int ci = h * 4 + mi * 2 + (g >> 1);
            *(bf16x4*)((char*)XA_s + tok * 512 + ((ci ^ (tok & 31)) << 4) + (g & 1) * 8) = pk;
        }
    }
    __syncthreads();

    // ---- phase 4: GEMM2 out[64 tok][256] = ao @ w_out + b_out.
    // B-frags from wopk: fully-coalesced 1KB wave loads.
    f32x4 acc2[4][2];
#pragma unroll
    for (int i = 0; i < 4; ++i) { acc2[i][0] = z4; acc2[i][1] = z4; }

    const bf16_t* wo = wopk + (size_t)wv * 8192;
    for (int ks = 0; ks < 8; ++ks) {
        bf16x8 af2[4], bf2[2];
#pragma unroll
        for (int mi = 0; mi < 4; ++mi) {
            int rr = 16 * mi + c;
            af2[mi] = *(const bf16x8*)((char*)XA_s + rr * 512 + (((4 * ks + g) ^ (rr & 31)) << 4));
        }
#pragma unroll
        for (int nj = 0; nj < 2; ++nj)
            bf2[nj] = *(const bf16x8*)(wo + (nj * 8 + ks) * 512 + lane * 8);
#pragma unroll
        for (int mi = 0; mi < 4; ++mi)
#pragma unroll
            for (int nj = 0; nj < 2; ++nj)
                acc2[mi][nj] = MFMA_BF16(af2[mi], bf2[nj], acc2[mi][nj]);
    }

#pragma unroll
    for (int nj = 0; nj < 2; ++nj) {
        int gcol = 32 * wv + 16 * nj + c;
        float bo = b_out[gcol];
#pragma unroll
        for (int mi = 0; mi < 4; ++mi)
#pragma unroll
            for (int rg = 0; rg < 4; ++rg) {
                int tok = 16 * mi + 4 * g + rg;
                size_t r = (size_t)(rbase + (tok >> 3) * 256 + (tok & 7));
                out[r * 256 + gcol] = acc2[mi][nj][rg] + bo;
            }
    }
}

// ---------------------------------------------------------------------------
extern "C" void kernel_launch(void* const* d_in, const int* in_sizes, int n_in,
                              void* d_out, int out_size, void* d_ws, size_t ws_size,
                              hipStream_t stream) {
    const float* x       = (const float*)d_in[0];
    const float* w_qkv   = (const float*)d_in[1];
    const float* pos_emb = (const float*)d_in[2];
    const float* w_out   = (const float*)d_in[3];
    const float* b_out   = (const float*)d_in[4];
    const int*   rel_idx = (const int*)d_in[5];

    char* ws = (char*)d_ws;
    bf16_t* wpk    = (bf16_t*)(ws + WPK_OFF);
    bf16_t* wopk   = (bf16_t*)(ws + WOPK_OFF);
    float*  biasPC = (float*)(ws + BIASPC_OFF);
    float*  out    = (float*)d_out;

    prep_kernel<<<1040, 256, 0, stream>>>(w_qkv, w_out, pos_emb, rel_idx,
                                          wpk, wopk, biasPC);
    fused_kernel<<<2048, 512, 0, stream>>>(x, wpk, biasPC, wopk, b_out, out);
}

// Round 16
// 138.401 us; speedup vs baseline: 1.2236x; 1.2236x over previous
//
#include <hip/hip_runtime.h>

// ---------------------------------------------------------------------------
// BaseWindowAttention on MI355X (gfx950) — FULLY FUSED single-pass pipeline
// x:[2,256,256,256]f32, w_qkv:[256,768]f32, pos_emb:[15,15]f32,
// w_out:[256,256]f32, b_out:[256]f32, rel_idx:[64,64,2]i32
// out:[2,256,256,256]f32
//
//  R16 = R14 champion (151.8us), byte-identical structure, plus s_setprio
//  around phase-2/phase-4 MFMA clusters (T5: phase 2 has no intra-phase
//  barriers -> waves drift across strips -> scheduler has MFMA-issuing vs
//  DS/L2-waiting waves to arbitrate).
//
//  Verified design points:
//   - 84 VGPR natural / 72KB LDS / 2 blocks x 8 waves = 16 waves/CU, which
//     exactly saturates the 65-128 VGPR occupancy tier (m69). Any fusion
//     adding a 64-reg accumulator block spills (R15: 169us, 270MB scratch).
//   - wpk/wopk pre-packed fragment-order weights: coalesced 1KB wave loads.
//   - operand-swapped Q/K strips: 8 b64 scratch writes vs 32 scalar.
//   - static names for all fragment arrays (rule #20; R11 = 1.1GB spill).
//   - never force min-waves/EU beyond natural fit (R2/R13/R15 spills).
// ---------------------------------------------------------------------------

typedef __bf16 bf16_t;
typedef __bf16 bf16x8 __attribute__((ext_vector_type(8)));
typedef __bf16 bf16x4 __attribute__((ext_vector_type(4)));
typedef float  f32x4  __attribute__((ext_vector_type(4)));

#define MFMA_BF16(a, b, c) __builtin_amdgcn_mfma_f32_16x16x32_bf16((a), (b), (c), 0, 0, 0)
#define SM_SCALE 0.17677669529663687f  // 32^-0.5

// ws layout (bytes)
#define WPK_OFF    0u         // bf16 [8h][3s][2ni][8ks][64 lane][8] = 384KB
#define WOPK_OFF   393216u    // bf16 [8wv][2nj][8ks][64 lane][8]   = 128KB
#define BIASPC_OFF 524288u    // f32  [64 e][64 lane]               = 16KB

// ---------------------------------------------------------------------------
__global__ __launch_bounds__(256) void prep_kernel(
    const float* __restrict__ w_qkv, const float* __restrict__ w_out,
    const float* __restrict__ pos_emb, const int* __restrict__ rel_idx,
    bf16_t* __restrict__ wpk, bf16_t* __restrict__ wopk,
    float* __restrict__ biasPC)
{
    int idx = blockIdx.x * 256 + threadIdx.x;
    if (idx < 196608) {
        // wpk: tile t = ((h*3+s)*2+ni)*8+ks, entry (lane,j)
        // value = w_qkv[k][n], n = s*256+h*32+ni*16+c, k = ks*32+g*8+j
        int j = idx & 7, lane = (idx >> 3) & 63, t = idx >> 9;
        int ks = t & 7, ni = (t >> 3) & 1, hs = t >> 4;
        int s = hs % 3, h = hs / 3;
        int c = lane & 15, g = lane >> 4;
        int n = s * 256 + h * 32 + ni * 16 + c;
        int k = ks * 32 + g * 8 + j;
        wpk[idx] = (bf16_t)w_qkv[k * 768 + n];
    } else if (idx < 262144) {
        // wopk: tile tt = (wv*2+nj)*8+ks, entry (lane,j)
        // value = w_out[k][n], n = 32wv+16nj+c, k = 32ks+8g+j
        int t2 = idx - 196608;
        int j = t2 & 7, lane = (t2 >> 3) & 63, tt = t2 >> 9;
        int ks = tt & 7, nj = (tt >> 3) & 1, wv = tt >> 4;
        int c = lane & 15, g = lane >> 4;
        wopk[t2] = (bf16_t)w_out[(32 * ks + 8 * g + j) * 256 + 32 * wv + 16 * nj + c];
    } else if (idx < 266240) {
        // biasPC[e][lane]: e = (ni,mi,rg) per-lane MFMA layout, transposed
        int t = idx - 262144;
        int e = t >> 6, lane = t & 63;
        int ni = e >> 4, mi = (e >> 2) & 3, rg = e & 3;
        int i = 16 * ni + (lane & 15);          // query index
        int j = 16 * mi + 4 * (lane >> 4) + rg; // key index
        int i0 = rel_idx[(i * 64 + j) * 2 + 0];
        int i1 = rel_idx[(i * 64 + j) * 2 + 1];
        biasPC[t] = pos_emb[i0 * 15 + i1];
    }
}

// ---------------------------------------------------------------------------
// Fully fused window kernel. Grid 2048 (one per window), 512 thr = 8 waves.
__global__ __launch_bounds__(512, 2) void fused_kernel(
    const float* __restrict__ x, const bf16_t* __restrict__ wpk,
    const float* __restrict__ biasPC, const bf16_t* __restrict__ wopk,
    const float* __restrict__ b_out, float* __restrict__ out)
{
    // XA_s: x-tile (phase 1-2), then AO tile (phase 3-4). 32KB.
    __shared__ __align__(16) bf16_t XA_s[64 * 256];
    // per-wave scratch 5KB: Q/K [64][40] | V^T [32][72] | P [2][1024]
    __shared__ __align__(16) bf16_t SB_s[8][2560];

    const int tid = threadIdx.x;
    const int lane = tid & 63, wv = tid >> 6;
    const int g = lane >> 4, c = lane & 15;
    const int b = blockIdx.x;
    const int h = wv;
    const int rbase = (b >> 10) * 65536 + ((b >> 5) & 31) * 2048 + (b & 31) * 8;

    bf16_t* SB = SB_s[wv];
    f32x4 z4 = {0.f, 0.f, 0.f, 0.f};

    // ---- early-issue B-frags for strip 0 (q): overlaps phase-1 staging
    const bf16_t* wb0 = wpk + (size_t)(h * 3 + 0) * 8192;
    bf16x8 bfr[2][8];
#pragma unroll
    for (int ni = 0; ni < 2; ++ni)
#pragma unroll
        for (int ks = 0; ks < 8; ++ks)
            bfr[ni][ks] = *(const bf16x8*)(wb0 + (ni * 8 + ks) * 512 + lane * 8);

    // ---- phase 1: x window -> Xs bf16 (2048 x 16B chunks, 4/thread)
#pragma unroll
    for (int jj = 0; jj < 4; ++jj) {
        int q = jj * 512 + tid;          // chunk index 0..2047
        int tok = q >> 5, ci = q & 31;   // 32 chunks per 64-token row
        int r = rbase + (tok >> 3) * 256 + (tok & 7);
        const f32x4* xp = (const f32x4*)(x + (size_t)r * 256 + ci * 8);
        f32x4 a = xp[0], bq = xp[1];
        bf16x8 t;
        t[0] = (bf16_t)a[0];  t[1] = (bf16_t)a[1];
        t[2] = (bf16_t)a[2];  t[3] = (bf16_t)a[3];
        t[4] = (bf16_t)bq[0]; t[5] = (bf16_t)bq[1];
        t[6] = (bf16_t)bq[2]; t[7] = (bf16_t)bq[3];
        *(bf16x8*)(XA_s + tok * 256 + ((ci ^ (tok & 31)) << 3)) = t;
    }
    __syncthreads();

    // ---- phase 2: per-head qkv GEMM, strip by strip
    bf16x8 qf[4], kf[4], vbA[2][2];

#pragma unroll
    for (int s = 0; s < 3; ++s) {
        if (s > 0) {   // strips 1,2: load held B-frags now
            const bf16_t* wb = wpk + (size_t)(h * 3 + s) * 8192;
#pragma unroll
            for (int ni = 0; ni < 2; ++ni)
#pragma unroll
                for (int ks = 0; ks < 8; ++ks)
                    bfr[ni][ks] = *(const bf16x8*)(wb + (ni * 8 + ks) * 512 + lane * 8);
        }

        if (s < 2) {
            // --- Q/K strip, operand-swapped MFMA:
            // acc[ni][mi]: dh = 16ni+4g+rg (rows), tok = 16mi+c (cols)
            f32x4 acc[2][4];
#pragma unroll
            for (int i = 0; i < 2; ++i)
#pragma unroll
                for (int j = 0; j < 4; ++j) acc[i][j] = z4;
#pragma unroll
            for (int ks = 0; ks < 8; ++ks) {
                bf16x8 af[4];
#pragma unroll
                for (int mi = 0; mi < 4; ++mi) {
                    int tok = 16 * mi + c;
                    af[mi] = *(const bf16x8*)(XA_s + tok * 256 + (((4 * ks + g) ^ (tok & 31)) << 3));
                }
                __builtin_amdgcn_s_setprio(1);
#pragma unroll
                for (int ni = 0; ni < 2; ++ni)
#pragma unroll
                    for (int mi = 0; mi < 4; ++mi)
                        acc[ni][mi] = MFMA_BF16(bfr[ni][ks], af[mi], acc[ni][mi]);
                __builtin_amdgcn_s_setprio(0);
            }
            // full-tile scratch round trip: 8 b64 writes, then 4 b128 reads.
            // Destinations are STATIC (qf or kf) — rule #20.
#pragma unroll
            for (int mi = 0; mi < 4; ++mi)
#pragma unroll
                for (int ni = 0; ni < 2; ++ni) {
                    bf16x4 pk;
#pragma unroll
                    for (int rg = 0; rg < 4; ++rg)
                        pk[rg] = (bf16_t)acc[ni][mi][rg];
                    *(bf16x4*)(SB + (16 * mi + c) * 40 + 16 * ni + 4 * g) = pk;
                }
            if (s == 0) {   // s is a literal in each unrolled copy
#pragma unroll
                for (int j = 0; j < 4; ++j)
                    qf[j] = *(const bf16x8*)(SB + (16 * j + c) * 40 + 8 * g);
            } else {
#pragma unroll
                for (int j = 0; j < 4; ++j)
                    kf[j] = *(const bf16x8*)(SB + (16 * j + c) * 40 + 8 * g);
            }
        } else {
            // --- V strip, standard order:
            // acc[mi][ni]: tok = 16mi+4g+rg (rows), dh = 16ni+c (cols)
            f32x4 acc[4][2];
#pragma unroll
            for (int i = 0; i < 4; ++i) { acc[i][0] = z4; acc[i][1] = z4; }
#pragma unroll
            for (int ks = 0; ks < 8; ++ks) {
                bf16x8 af[4];
#pragma unroll
                for (int mi = 0; mi < 4; ++mi) {
                    int tok = 16 * mi + c;
                    af[mi] = *(const bf16x8*)(XA_s + tok * 256 + (((4 * ks + g) ^ (tok & 31)) << 3));
                }
                __builtin_amdgcn_s_setprio(1);
#pragma unroll
                for (int mi = 0; mi < 4; ++mi) {
                    acc[mi][0] = MFMA_BF16(af[mi], bfr[0][ks], acc[mi][0]);
                    acc[mi][1] = MFMA_BF16(af[mi], bfr[1][ks], acc[mi][1]);
                }
                __builtin_amdgcn_s_setprio(0);
            }
            // V^T [32][72] scratch: 8 b64 writes, then 4 b128 reads
#pragma unroll
            for (int mi = 0; mi < 4; ++mi)
#pragma unroll
                for (int ni = 0; ni < 2; ++ni) {
                    bf16x4 pk;
#pragma unroll
                    for (int rg = 0; rg < 4; ++rg)
                        pk[rg] = (bf16_t)acc[mi][ni][rg];
                    *(bf16x4*)(SB + (16 * ni + c) * 72 + 16 * mi + 4 * g) = pk;
                }
#pragma unroll
            for (int ks2 = 0; ks2 < 2; ++ks2) {
                vbA[ks2][0] = *(const bf16x8*)(SB + c * 72 + 32 * ks2 + 8 * g);
                vbA[ks2][1] = *(const bf16x8*)(SB + (16 + c) * 72 + 32 * ks2 + 8 * g);
            }
        }
    }
    __syncthreads();   // all waves done with Xs; XA_s becomes AO tile

    // ---- phase 3: attention per head (P dbuf in SB; bias from biasPC)
    bf16_t* Pw = SB;
#pragma unroll
    for (int ni = 0; ni < 4; ++ni) {
        f32x4 s[4];
        __builtin_amdgcn_s_setprio(1);
#pragma unroll
        for (int mi = 0; mi < 4; ++mi)
            s[mi] = MFMA_BF16(kf[mi], qf[ni], z4);
        __builtin_amdgcn_s_setprio(0);

        float mx = -1e30f;
#pragma unroll
        for (int mi = 0; mi < 4; ++mi) {
#pragma unroll
            for (int rg = 0; rg < 4; ++rg) {
                float bb = biasPC[(ni * 16 + mi * 4 + rg) * 64 + lane];
                float t = fmaf(s[mi][rg], SM_SCALE, bb);
                s[mi][rg] = t;
                mx = fmaxf(mx, t);
            }
        }
        mx = fmaxf(mx, __shfl_xor(mx, 16));
        mx = fmaxf(mx, __shfl_xor(mx, 32));
        float sm = 0.f;
#pragma unroll
        for (int mi = 0; mi < 4; ++mi)
#pragma unroll
            for (int rg = 0; rg < 4; ++rg) {
                float p = __expf(s[mi][rg] - mx);
                s[mi][rg] = p;
                sm += p;
            }
        sm += __shfl_xor(sm, 16);
        sm += __shfl_xor(sm, 32);
        float inv = 1.0f / sm;

        bf16_t* Pl = Pw + (ni & 1) * 1024;   // double-buffered 2KB tile
#pragma unroll
        for (int mi = 0; mi < 4; ++mi) {
            bf16x4 pk;
#pragma unroll
            for (int rg = 0; rg < 4; ++rg) pk[rg] = (bf16_t)s[mi][rg];
            *(bf16x4*)(Pl + c * 64 + (((2 * mi + (g >> 1)) ^ (c & 7)) << 3) + 4 * (g & 1)) = pk;
        }

        // O^T = V^T P^T : lane(c,g) -> O^T[dh=16mi+4g+rg][tok=16ni+c]
        f32x4 o0 = z4, o1 = z4;
        __builtin_amdgcn_s_setprio(1);
#pragma unroll
        for (int ks = 0; ks < 2; ++ks) {
            bf16x8 pa = *(const bf16x8*)(Pl + c * 64 + (((4 * ks + g) ^ (c & 7)) << 3));
            o0 = MFMA_BF16(vbA[ks][0], pa, o0);
            o1 = MFMA_BF16(vbA[ks][1], pa, o1);
        }
        __builtin_amdgcn_s_setprio(0);
        // normalize (inv is per q-row, uniform over g) + AO write (b64)
        int tok = 16 * ni + c;
#pragma unroll
        for (int mi = 0; mi < 2; ++mi) {
            f32x4 ov = (mi == 0) ? o0 : o1;
            bf16x4 pk;
#pragma unroll
            for (int rg = 0; rg < 4; ++rg) pk[rg] = (bf16_t)(ov[rg] * inv);
            int ci = h * 4 + mi * 2 + (g >> 1);
            *(bf16x4*)((char*)XA_s + tok * 512 + ((ci ^ (tok & 31)) << 4) + (g & 1) * 8) = pk;
        }
    }
    __syncthreads();

    // ---- phase 4: GEMM2 out[64 tok][256] = ao @ w_out + b_out.
    // B-frags from wopk: fully-coalesced 1KB wave loads.
    f32x4 acc2[4][2];
#pragma unroll
    for (int i = 0; i < 4; ++i) { acc2[i][0] = z4; acc2[i][1] = z4; }

    const bf16_t* wo = wopk + (size_t)wv * 8192;
    for (int ks = 0; ks < 8; ++ks) {
        bf16x8 af2[4], bf2[2];
#pragma unroll
        for (int mi = 0; mi < 4; ++mi) {
            int rr = 16 * mi + c;
            af2[mi] = *(const bf16x8*)((char*)XA_s + rr * 512 + (((4 * ks + g) ^ (rr & 31)) << 4));
        }
#pragma unroll
        for (int nj = 0; nj < 2; ++nj)
            bf2[nj] = *(const bf16x8*)(wo + (nj * 8 + ks) * 512 + lane * 8);
        __builtin_amdgcn_s_setprio(1);
#pragma unroll
        for (int mi = 0; mi < 4; ++mi)
#pragma unroll
            for (int nj = 0; nj < 2; ++nj)
                acc2[mi][nj] = MFMA_BF16(af2[mi], bf2[nj], acc2[mi][nj]);
        __builtin_amdgcn_s_setprio(0);
    }

#pragma unroll
    for (int nj = 0; nj < 2; ++nj) {
        int gcol = 32 * wv + 16 * nj + c;
        float bo = b_out[gcol];
#pragma unroll
        for (int mi = 0; mi < 4; ++mi)
#pragma unroll
            for (int rg = 0; rg < 4; ++rg) {
                int tok = 16 * mi + 4 * g + rg;
                size_t r = (size_t)(rbase + (tok >> 3) * 256 + (tok & 7));
                out[r * 256 + gcol] = acc2[mi][nj][rg] + bo;
            }
    }
}

// ---------------------------------------------------------------------------
extern "C" void kernel_launch(void* const* d_in, const int* in_sizes, int n_in,
                              void* d_out, int out_size, void* d_ws, size_t ws_size,
                              hipStream_t stream) {
    const float* x       = (const float*)d_in[0];
    const float* w_qkv   = (const float*)d_in[1];
    const float* pos_emb = (const float*)d_in[2];
    const float* w_out   = (const float*)d_in[3];
    const float* b_out   = (const float*)d_in[4];
    const int*   rel_idx = (const int*)d_in[5];

    char* ws = (char*)d_ws;
    bf16_t* wpk    = (bf16_t*)(ws + WPK_OFF);
    bf16_t* wopk   = (bf16_t*)(ws + WOPK_OFF);
    float*  biasPC = (float*)(ws + BIASPC_OFF);
    float*  out    = (float*)d_out;

    prep_kernel<<<1040, 256, 0, stream>>>(w_qkv, w_out, pos_emb, rel_idx,
                                          wpk, wopk, biasPC);
    fused_kernel<<<2048, 512, 0, stream>>>(x, wpk, biasPC, wopk, b_out, out);
}